// Round 29
// baseline (1151.261 us; speedup 1.0000x reference)
//
#include <hip/hip_runtime.h>
#include <hip/hip_bf16.h>

#define N_NODES 100000
#define N_EDGES 3200000
#define FEAT 256
#define HIDDEN 32
#define EMBED 16
#define NPB 128                                // nodes per bin
#define NBIN ((N_NODES + NPB - 1) / NPB)       // 782
#define CAPB 4608                              // bin capacity (mean 4096 + 8 sigma)
#define OCAP 8192                              // overflow list capacity
#define GR 128                                 // gemm1 tile rows
#define G1N 32                                 // nodes per gather1 block
#define G1CAP 2048                             // LDS entries
#define G2N 64                                 // nodes per gather2 block
#define G2CAP 3072                             // LDS entries
#define PEPB 3072                              // edges per partition block
#define PBLK ((N_EDGES + PEPB - 1) / PEPB)     // 1042
#define OMS 784                                // offm row stride (782 bins + sentinel + pad)
#define RPT 5                                  // runs per thread in k_build (5*256 >= 1042)
#define NSK (NPB * 16)                         // sub-keys: node x 16 src-tiles

// ---------------- pass 1: per-block bin-grouped chunk + offset row ----------
__global__ __launch_bounds__(256, 4) void k_part(
        const int* __restrict__ row, const int* __restrict__ col,
        const float* __restrict__ ew, int* __restrict__ offm,
        int2* __restrict__ chunks, int* __restrict__ ocur) {
    __shared__ int2 sed[PEPB];                 // 24576 B staged edges (grouped)
    __shared__ int shist[NBIN];                // counts -> local excl offsets
    __shared__ int scur[NBIN];                 // scan scratch, then cursors
    const int tid = threadIdx.x;
    const int blk = blockIdx.x;
    const int e0 = blk * PEPB;
    const int ne = min(PEPB, N_EDGES - e0);
    if (blk == 0 && tid == 0) *ocur = 0;

    for (int i = tid; i < NBIN; i += 256) shist[i] = 0;
    __syncthreads();
    for (int i = tid; i < ne; i += 256) atomicAdd(&shist[col[e0 + i] >> 7], 1);
    __syncthreads();
    int l[4];
    int s = 0;
#pragma unroll
    for (int k = 0; k < 4; ++k) {
        int b = tid * 4 + k;
        l[k] = (b < NBIN) ? shist[b] : 0;
        s += l[k];
    }
    scur[tid] = s;
    __syncthreads();
    for (int d = 1; d < 256; d <<= 1) {
        int t = (tid >= d) ? scur[tid - d] : 0;
        __syncthreads();
        scur[tid] += t;
        __syncthreads();
    }
    int ex = scur[tid] - s;
    __syncthreads();
#pragma unroll
    for (int k = 0; k < 4; ++k) {
        int b = tid * 4 + k;
        if (b < NBIN) {
            shist[b] = ex;
            scur[b] = ex;
            ex += l[k];
        }
    }
    __syncthreads();
    for (int b = tid; b < NBIN; b += 256) offm[blk * OMS + b] = shist[b];
    if (tid == 0) offm[blk * OMS + NBIN] = ne;
    for (int i = tid; i < ne; i += 256) {
        int e = e0 + i;
        int c = col[e];
        int b = c >> 7;
        int p = atomicAdd(&scur[b], 1);        // LDS atomic
        sed[p] = make_int2(((c & (NPB - 1)) << 17) | row[e], __float_as_int(ew[e]));
    }
    __syncthreads();
    for (int i = tid; i < ne; i += 256) chunks[(size_t)blk * PEPB + i] = sed[i];
}

// ---------------- pass 2: per-bin gather + group + FULL deg->dis + off2 ----
__global__ __launch_bounds__(256) void k_build(
        const int* __restrict__ offm, const int2* __restrict__ chunks,
        int2* __restrict__ binned, float* __restrict__ dis,
        int2* __restrict__ off2, int* __restrict__ ocur, int4* __restrict__ olist) {
    __shared__ int2 se[CAPB];                      // 36864 B
    __shared__ int scnt[NSK];                      //  8192 B (offsets, then cursors)
    __shared__ float sdeg[NPB];
    __shared__ int spart[256];
    const int bin = blockIdx.x, tid = threadIdx.x;
    const size_t base = (size_t)bin * CAPB;

    for (int i = tid; i < NSK; i += 256) scnt[i] = 0;
    for (int i = tid; i < NPB; i += 256) sdeg[i] = 0.f;
    int st[RPT], ln[RPT];
    int s = 0;
#pragma unroll
    for (int r = 0; r < RPT; ++r) {
        int k = tid * RPT + r;
        int a = 0, b2 = 0;
        if (k < PBLK) {
            a = offm[k * OMS + bin];
            b2 = offm[k * OMS + bin + 1];
        }
        st[r] = a;
        ln[r] = b2 - a;
        s += ln[r];
    }
    spart[tid] = s;
    __syncthreads();
    for (int d = 1; d < 256; d <<= 1) {
        int t = (tid >= d) ? spart[tid - d] : 0;
        __syncthreads();
        spart[tid] += t;
        __syncthreads();
    }
    int ex = spart[tid] - s;
    const int nTot = spart[255];
    const int n = min(nTot, CAPB);
    int dp = ex;
#pragma unroll
    for (int r = 0; r < RPT; ++r) {
        int k = tid * RPT + r;
        if (k < PBLK) {
            const int2* src = chunks + (size_t)k * PEPB + st[r];
            for (int j = 0; j < ln[r]; ++j) {
                int2 v = src[j];
                int lc = v.x >> 17;
                int dst = dp + j;
                atomicAdd(&sdeg[lc], __int_as_float(v.y));  // ALL edges count
                if (dst < CAPB) {
                    se[dst] = v;
                    atomicAdd(&scnt[lc * 16 + ((v.x & 0x1FFFF) >> 13)], 1);
                } else {
                    int q = atomicAdd(ocur, 1);
                    if (q < OCAP)
                        olist[q] = make_int4(v.x & 0x1FFFF, bin * NPB + lc, v.y, 0);
                }
            }
            dp += ln[r];
        }
    }
    __syncthreads();
    int l8[8];
    int s2 = 0;
#pragma unroll
    for (int k = 0; k < 8; ++k) {
        l8[k] = scnt[tid * 8 + k];
        s2 += l8[k];
    }
    spart[tid] = s2;
    __syncthreads();
    for (int d = 1; d < 256; d <<= 1) {
        int t = (tid >= d) ? spart[tid - d] : 0;
        __syncthreads();
        spart[tid] += t;
        __syncthreads();
    }
    int ex2 = spart[tid] - s2;
#pragma unroll
    for (int k = 0; k < 8; ++k) {
        scnt[tid * 8 + k] = ex2;
        ex2 += l8[k];
    }
    __syncthreads();
    if (tid < NPB) {
        int node = bin * NPB + tid;
        if (node < N_NODES) {
            int stn = scnt[tid * 16];
            int en = (tid == NPB - 1) ? n : scnt[(tid + 1) * 16];
            off2[node] = make_int2((int)base + stn, en - stn);
            float dg = sdeg[tid] + 1.0f;   // + self loop; always > 0
            dis[node] = rsqrtf(dg);
        }
    }
    __syncthreads();   // off2/en reads done; scnt now reusable as cursors
    for (int i = tid; i < n; i += 256) {
        int2 v = se[i];
        int lc = v.x >> 17, src2 = v.x & 0x1FFFF;
        int p = atomicAdd(&scnt[lc * 16 + (src2 >> 13)], 1);  // LDS atomic
        binned[base + p] = make_int2(src2, v.y);              // {src, raw ew}
    }
}

// ---------------- layer 1 GEMM: h' = (x @ W1^T) * dis ----------------
// BOTH x and W phase-staged (23KB LDS) + VGPR capped at 128 via
// __launch_bounds__(256,4): 4 blocks/CU, 16 waves (was 3 blocks/12 waves,
// VGPR=148-gated). Same reg->LDS pipelined rhythm as R19.
__global__ __launch_bounds__(256, 4) void k_gemm1(
        const float* __restrict__ x, const float* __restrict__ W1,
        const float* __restrict__ dis, float* __restrict__ h) {
    __shared__ float sx[GR][36];       // 18432 B
    __shared__ float sw[HIDDEN][36];   //  4608 B (phase-local W)

    const int tid = threadIdx.x;
    const size_t base = (size_t)blockIdx.x * GR;
    const float4* x4 = (const float4*)x;
    const float4* w4 = (const float4*)W1;
    const int rs = tid >> 3;   // staging row group: rows rs+32m
    const int ks = tid & 7;    // staging kq within phase
    const int wf = tid >> 3;   // W staging: row (reuse rs range 0..31)
    // W stage map: thread i stages float4 (f = i>>3, kq = i&7)

    // prologue: phase-0 x and W into regs, then LDS
    float4 stg[4], stgw;
#pragma unroll
    for (int m = 0; m < 4; ++m) {
        int rr = rs + 32 * m;
        stg[m] = make_float4(0.f, 0.f, 0.f, 0.f);
        if (base + rr < N_NODES) stg[m] = x4[(base + rr) * 64 + ks];
    }
    stgw = w4[wf * 64 + ks];
#pragma unroll
    for (int m = 0; m < 4; ++m) *(float4*)&sx[rs + 32 * m][ks * 4] = stg[m];
    *(float4*)&sw[wf][ks * 4] = stgw;
    __syncthreads();

    const int r0 = tid >> 3;
    const int c0 = tid & 7;
    float acc[4][4] = {};

    for (int p = 0; p < 8; ++p) {
        if (p < 7) {
            // issue next phase's loads (in flight across the compute below)
#pragma unroll
            for (int m = 0; m < 4; ++m) {
                int rr = rs + 32 * m;
                stg[m] = make_float4(0.f, 0.f, 0.f, 0.f);
                if (base + rr < N_NODES) stg[m] = x4[(base + rr) * 64 + (p + 1) * 8 + ks];
            }
            stgw = w4[wf * 64 + (p + 1) * 8 + ks];
        }
#pragma unroll
        for (int kq = 0; kq < 8; ++kq) {
            float4 xa[4], wv[4];
#pragma unroll
            for (int m = 0; m < 4; ++m) xa[m] = *(const float4*)&sx[r0 + 32 * m][kq * 4];
#pragma unroll
            for (int j = 0; j < 4; ++j) wv[j] = *(const float4*)&sw[c0 + 8 * j][kq * 4];
#pragma unroll
            for (int m = 0; m < 4; ++m)
#pragma unroll
                for (int j = 0; j < 4; ++j)
                    acc[m][j] += xa[m].x * wv[j].x + xa[m].y * wv[j].y +
                                 xa[m].z * wv[j].z + xa[m].w * wv[j].w;
        }
        __syncthreads();
        if (p < 7) {
#pragma unroll
            for (int m = 0; m < 4; ++m) *(float4*)&sx[rs + 32 * m][ks * 4] = stg[m];
            *(float4*)&sw[wf][ks * 4] = stgw;
            __syncthreads();
        }
    }

#pragma unroll
    for (int m = 0; m < 4; ++m) {
        size_t r = base + r0 + 32 * m;
        if (r < N_NODES) {
            float ds = dis[r];
#pragma unroll
            for (int j = 0; j < 4; ++j) h[r * HIDDEN + c0 + 8 * j] = acc[m][j] * ds;
        }
    }
}

// ---- FUSED layer-1 gather + gemm2 (h is pre-scaled h' = h*dis) ----
__global__ __launch_bounds__(256) void k_gather1(
        const int2* __restrict__ off2, const int2* __restrict__ csr,
        const float* __restrict__ h, const float* __restrict__ dis,
        const float* __restrict__ b1, const float* __restrict__ W2,
        const int* __restrict__ ocur, const int4* __restrict__ olist,
        float* __restrict__ h2) {
    __shared__ int2 sc[G1CAP];                 // 16384 B csr window
    __shared__ float sw2[EMBED][HIDDEN + 1];   //  2112 B (stride 33)
    __shared__ float sout[G1N][HIDDEN + 1];    //  4224 B relu(out1)
    __shared__ int s_start, s_n, s_ov;
    const int tid = threadIdx.x;
    const int node0 = blockIdx.x * G1N;        // 100000 = 32*3125 exact
    if (tid == 0) {
        int2 a = off2[node0];
        int2 b = off2[node0 + G1N - 1];
        s_start = a.x;
        s_n = b.x + b.y - a.x;
        s_ov = *ocur;
    }
    for (int i = tid; i < EMBED * HIDDEN; i += 256) sw2[i >> 5][i & 31] = W2[i];
    __syncthreads();
    const int start = s_start, n = s_n, ov = min(s_ov, OCAP);
    const bool fit = (n <= G1CAP);
    if (fit) for (int i = tid; i < n; i += 256) sc[i] = csr[start + i];
    __syncthreads();

    const int node = node0 + (tid >> 3);
    const int og = tid & 7;
    float d = dis[node];
    float4 self = *(const float4*)(h + (size_t)node * HIDDEN + og * 4);
    float4 bv = *(const float4*)(b1 + og * 4);
    float4 acc = make_float4(0.f, 0.f, 0.f, 0.f);

    int2 o = off2[node];
    for (int j = 0; j < o.y; ++j) {
        int2 v = fit ? sc[o.x - start + j] : csr[o.x + j];
        float w = __int_as_float(v.y);           // raw ew
        const float4 hv = *(const float4*)(h + (size_t)v.x * HIDDEN + og * 4);
        acc.x += hv.x * w; acc.y += hv.y * w; acc.z += hv.z * w; acc.w += hv.w * w;
    }
    float4 res = make_float4((acc.x + self.x) * d + bv.x,
                             (acc.y + self.y) * d + bv.y,
                             (acc.z + self.z) * d + bv.z,
                             (acc.w + self.w) * d + bv.w);
    if (ov > 0) {  // exact overflow fallback (never taken in practice)
        for (int q = 0; q < ov; ++q) {
            int4 t = olist[q];
            if (t.y == node) {
                float w = __int_as_float(t.z) * d;  // h' includes dis[src]
                const float4 hv = *(const float4*)(h + (size_t)t.x * HIDDEN + og * 4);
                res.x += hv.x * w; res.y += hv.y * w;
                res.z += hv.z * w; res.w += hv.w * w;
            }
        }
    }
    // relu + stage
    *(float4*)&sout[tid >> 3][og * 4] =
        make_float4(fmaxf(res.x, 0.f), fmaxf(res.y, 0.f),
                    fmaxf(res.z, 0.f), fmaxf(res.w, 0.f));
    __syncthreads();
    // h2' = (relu(out1) @ W2^T) * dis : 32 nodes x 16 feats, 2 per thread
    const int n2 = tid >> 3;
    const int f2 = (tid & 7) * 2;
    float a0 = 0.f, a1 = 0.f;
#pragma unroll
    for (int k = 0; k < HIDDEN; ++k) {
        float r = sout[n2][k];
        a0 += r * sw2[f2][k];
        a1 += r * sw2[f2 + 1][k];
    }
    h2[(size_t)(node0 + n2) * EMBED + f2] = a0 * d;
    h2[(size_t)(node0 + n2) * EMBED + f2 + 1] = a1 * d;
}

// ---- layer 2 gather (h2 is pre-scaled h2' = h2*dis): out = gcn2 ----
__global__ __launch_bounds__(256) void k_gather2(
        const int2* __restrict__ off2, const int2* __restrict__ csr,
        const float* __restrict__ h2, const float* __restrict__ dis,
        const float* __restrict__ b2, const int* __restrict__ ocur,
        const int4* __restrict__ olist, float* __restrict__ out) {
    __shared__ int2 sc[G2CAP];
    __shared__ int s_start, s_n, s_ov;
    const int tid = threadIdx.x;
    const int node0 = blockIdx.x * G2N;
    const int lastn = min(node0 + G2N, N_NODES) - 1;
    if (tid == 0) {
        int2 a = off2[node0];
        int2 b = off2[lastn];
        s_start = a.x;
        s_n = b.x + b.y - a.x;
        s_ov = *ocur;
    }
    __syncthreads();
    const int start = s_start, n = s_n, ov = min(s_ov, OCAP);
    const bool fit = (n <= G2CAP);
    if (fit) for (int i = tid; i < n; i += 256) sc[i] = csr[start + i];
    __syncthreads();

    const int node = node0 + (tid >> 2);
    const int og = tid & 3;
    if (node >= N_NODES) return;
    float d = dis[node];
    float4 self = *(const float4*)(h2 + (size_t)node * EMBED + og * 4);
    float4 bv = *(const float4*)(b2 + og * 4);
    float4 acc = make_float4(0.f, 0.f, 0.f, 0.f);

    int2 o = off2[node];
    for (int j = 0; j < o.y; ++j) {
        int2 v = fit ? sc[o.x - start + j] : csr[o.x + j];
        float w = __int_as_float(v.y);           // raw ew
        const float4 hv = *(const float4*)(h2 + (size_t)v.x * EMBED + og * 4);
        acc.x += hv.x * w; acc.y += hv.y * w; acc.z += hv.z * w; acc.w += hv.w * w;
    }
    float4 res = make_float4((acc.x + self.x) * d + bv.x,
                             (acc.y + self.y) * d + bv.y,
                             (acc.z + self.z) * d + bv.z,
                             (acc.w + self.w) * d + bv.w);
    if (ov > 0) {  // exact overflow fallback
        for (int q = 0; q < ov; ++q) {
            int4 t = olist[q];
            if (t.y == node) {
                float w = __int_as_float(t.z) * d;  // h2' includes dis[src]
                const float4 hv = *(const float4*)(h2 + (size_t)t.x * EMBED + og * 4);
                res.x += hv.x * w; res.y += hv.y * w;
                res.z += hv.z * w; res.w += hv.w * w;
            }
        }
    }
    *(float4*)(out + (size_t)node * EMBED + og * 4) = res;
}

extern "C" void kernel_launch(void* const* d_in, const int* in_sizes, int n_in,
                              void* d_out, int out_size, void* d_ws, size_t ws_size,
                              hipStream_t stream) {
    const float* x  = (const float*)d_in[0];
    const int*   ei = (const int*)d_in[1];  // [2, E] int32
    const float* ew = (const float*)d_in[2];
    const float* W1 = (const float*)d_in[3];
    const float* b1 = (const float*)d_in[4];
    const float* W2 = (const float*)d_in[5];
    const float* b2 = (const float*)d_in[6];
    float* out = (float*)d_out;

    const int* row = ei;            // source
    const int* col = ei + N_EDGES;  // target

    // ws layout:
    // off2[N] int2 | binned[NBIN*CAPB] int2 | dis[N] f32 |
    // offm[PBLK*OMS] int | ocur[4] int | olist[OCAP] int4 |
    // big: chunks[PBLK*PEPB] int2  ALIASES  h[32N] + h2[16N]
    int2*  off2   = (int2*)d_ws;
    int2*  binned = off2 + N_NODES;
    float* dis    = (float*)(binned + (size_t)NBIN * CAPB);
    int*   offm   = (int*)(dis + N_NODES);
    int*   ocur   = offm + (size_t)PBLK * OMS;
    int4*  olist  = (int4*)(ocur + 4);
    void*  big    = (void*)(olist + OCAP);
    int2*  chunks = (int2*)big;
    float* h      = (float*)big;               // alias: chunks dead before gemm1
    float* h2     = h + (size_t)N_NODES * HIDDEN;

    const int B = 256;

    k_part<<<PBLK, B, 0, stream>>>(row, col, ew, offm, chunks, ocur);
    k_build<<<NBIN, B, 0, stream>>>(offm, chunks, binned, dis, off2, ocur, olist);
    k_gemm1<<<(N_NODES + GR - 1) / GR, B, 0, stream>>>(x, W1, dis, h);
    k_gather1<<<N_NODES / G1N, B, 0, stream>>>(off2, binned, h, dis, b1, W2, ocur, olist, h2);
    k_gather2<<<(N_NODES + G2N - 1) / G2N, B, 0, stream>>>(off2, binned, h2, dis, b2, ocur, olist, out);
}

// Round 30
// 266.288 us; speedup vs baseline: 4.3234x; 4.3234x over previous
//
#include <hip/hip_runtime.h>
#include <hip/hip_bf16.h>

#define N_NODES 100000
#define N_EDGES 3200000
#define FEAT 256
#define HIDDEN 32
#define EMBED 16
#define NPB 128                                // nodes per bin
#define NBIN ((N_NODES + NPB - 1) / NPB)       // 782
#define CAPB 4608                              // bin capacity (mean 4096 + 8 sigma)
#define OCAP 8192                              // overflow list capacity
#define GR 128                                 // gemm1 tile rows
#define G1N 32                                 // nodes per gather1 block
#define G1CAP 2048                             // LDS entries
#define G2N 64                                 // nodes per gather2 block
#define G2CAP 3072                             // LDS entries
#define PEPB 3072                              // edges per partition block
#define PBLK ((N_EDGES + PEPB - 1) / PEPB)     // 1042
#define OMS 784                                // offm row stride (782 bins + sentinel + pad)
#define RPT 5                                  // runs per thread in k_build (5*256 >= 1042)
#define NSK (NPB * 16)                         // sub-keys: node x 16 src-tiles

// ---------------- pass 1: per-block bin-grouped chunk + offset row ----------
__global__ __launch_bounds__(256, 4) void k_part(
        const int* __restrict__ row, const int* __restrict__ col,
        const float* __restrict__ ew, int* __restrict__ offm,
        int2* __restrict__ chunks, int* __restrict__ ocur) {
    __shared__ int2 sed[PEPB];                 // 24576 B staged edges (grouped)
    __shared__ int shist[NBIN];                // counts -> local excl offsets
    __shared__ int scur[NBIN];                 // scan scratch, then cursors
    const int tid = threadIdx.x;
    const int blk = blockIdx.x;
    const int e0 = blk * PEPB;
    const int ne = min(PEPB, N_EDGES - e0);
    if (blk == 0 && tid == 0) *ocur = 0;

    for (int i = tid; i < NBIN; i += 256) shist[i] = 0;
    __syncthreads();
    for (int i = tid; i < ne; i += 256) atomicAdd(&shist[col[e0 + i] >> 7], 1);
    __syncthreads();
    int l[4];
    int s = 0;
#pragma unroll
    for (int k = 0; k < 4; ++k) {
        int b = tid * 4 + k;
        l[k] = (b < NBIN) ? shist[b] : 0;
        s += l[k];
    }
    scur[tid] = s;
    __syncthreads();
    for (int d = 1; d < 256; d <<= 1) {
        int t = (tid >= d) ? scur[tid - d] : 0;
        __syncthreads();
        scur[tid] += t;
        __syncthreads();
    }
    int ex = scur[tid] - s;
    __syncthreads();
#pragma unroll
    for (int k = 0; k < 4; ++k) {
        int b = tid * 4 + k;
        if (b < NBIN) {
            shist[b] = ex;
            scur[b] = ex;
            ex += l[k];
        }
    }
    __syncthreads();
    for (int b = tid; b < NBIN; b += 256) offm[blk * OMS + b] = shist[b];
    if (tid == 0) offm[blk * OMS + NBIN] = ne;
    for (int i = tid; i < ne; i += 256) {
        int e = e0 + i;
        int c = col[e];
        int b = c >> 7;
        int p = atomicAdd(&scur[b], 1);        // LDS atomic
        sed[p] = make_int2(((c & (NPB - 1)) << 17) | row[e], __float_as_int(ew[e]));
    }
    __syncthreads();
    for (int i = tid; i < ne; i += 256) chunks[(size_t)blk * PEPB + i] = sed[i];
}

// ---------------- pass 2: per-bin gather + group + FULL deg->dis + off2 ----
__global__ __launch_bounds__(256) void k_build(
        const int* __restrict__ offm, const int2* __restrict__ chunks,
        int2* __restrict__ binned, float* __restrict__ dis,
        int2* __restrict__ off2, int* __restrict__ ocur, int4* __restrict__ olist) {
    __shared__ int2 se[CAPB];                      // 36864 B
    __shared__ int scnt[NSK];                      //  8192 B (offsets, then cursors)
    __shared__ float sdeg[NPB];
    __shared__ int spart[256];
    const int bin = blockIdx.x, tid = threadIdx.x;
    const size_t base = (size_t)bin * CAPB;

    for (int i = tid; i < NSK; i += 256) scnt[i] = 0;
    for (int i = tid; i < NPB; i += 256) sdeg[i] = 0.f;
    int st[RPT], ln[RPT];
    int s = 0;
#pragma unroll
    for (int r = 0; r < RPT; ++r) {
        int k = tid * RPT + r;
        int a = 0, b2 = 0;
        if (k < PBLK) {
            a = offm[k * OMS + bin];
            b2 = offm[k * OMS + bin + 1];
        }
        st[r] = a;
        ln[r] = b2 - a;
        s += ln[r];
    }
    spart[tid] = s;
    __syncthreads();
    for (int d = 1; d < 256; d <<= 1) {
        int t = (tid >= d) ? spart[tid - d] : 0;
        __syncthreads();
        spart[tid] += t;
        __syncthreads();
    }
    int ex = spart[tid] - s;
    const int nTot = spart[255];
    const int n = min(nTot, CAPB);
    int dp = ex;
#pragma unroll
    for (int r = 0; r < RPT; ++r) {
        int k = tid * RPT + r;
        if (k < PBLK) {
            const int2* src = chunks + (size_t)k * PEPB + st[r];
            for (int j = 0; j < ln[r]; ++j) {
                int2 v = src[j];
                int lc = v.x >> 17;
                int dst = dp + j;
                atomicAdd(&sdeg[lc], __int_as_float(v.y));  // ALL edges count
                if (dst < CAPB) {
                    se[dst] = v;
                    atomicAdd(&scnt[lc * 16 + ((v.x & 0x1FFFF) >> 13)], 1);
                } else {
                    int q = atomicAdd(ocur, 1);
                    if (q < OCAP)
                        olist[q] = make_int4(v.x & 0x1FFFF, bin * NPB + lc, v.y, 0);
                }
            }
            dp += ln[r];
        }
    }
    __syncthreads();
    int l8[8];
    int s2 = 0;
#pragma unroll
    for (int k = 0; k < 8; ++k) {
        l8[k] = scnt[tid * 8 + k];
        s2 += l8[k];
    }
    spart[tid] = s2;
    __syncthreads();
    for (int d = 1; d < 256; d <<= 1) {
        int t = (tid >= d) ? spart[tid - d] : 0;
        __syncthreads();
        spart[tid] += t;
        __syncthreads();
    }
    int ex2 = spart[tid] - s2;
#pragma unroll
    for (int k = 0; k < 8; ++k) {
        scnt[tid * 8 + k] = ex2;
        ex2 += l8[k];
    }
    __syncthreads();
    if (tid < NPB) {
        int node = bin * NPB + tid;
        if (node < N_NODES) {
            int stn = scnt[tid * 16];
            int en = (tid == NPB - 1) ? n : scnt[(tid + 1) * 16];
            off2[node] = make_int2((int)base + stn, en - stn);
            float dg = sdeg[tid] + 1.0f;   // + self loop; always > 0
            dis[node] = rsqrtf(dg);
        }
    }
    __syncthreads();   // off2/en reads done; scnt now reusable as cursors
    for (int i = tid; i < n; i += 256) {
        int2 v = se[i];
        int lc = v.x >> 17, src2 = v.x & 0x1FFFF;
        int p = atomicAdd(&scnt[lc * 16 + (src2 >> 13)], 1);  // LDS atomic
        binned[base + p] = make_int2(src2, v.y);              // {src, raw ew}
    }
}

// ---------------- layer 1 GEMM: h' = (x @ W1^T) * dis (R28 variant) --------
// W staged ONCE in LDS (sw[32][260]); x in 8 K-phases (sx[128][36]);
// 51.7KB LDS, VGPR 148, 3 blocks/CU — measured 77us; VGPR-capping spills
// (R29: 974us), global-W is latency-bound (R21: 165us). This is the optimum.
__global__ __launch_bounds__(256) void k_gemm1(
        const float* __restrict__ x, const float* __restrict__ W1,
        const float* __restrict__ dis, float* __restrict__ h) {
    __shared__ float sx[GR][36];       // 18432 B
    __shared__ float sw[HIDDEN][260];  // 33280 B

    const int tid = threadIdx.x;
    const size_t base = (size_t)blockIdx.x * GR;
    const float4* x4 = (const float4*)x;
    const float4* w4 = (const float4*)W1;
    const int rs = tid >> 3;
    const int ks = tid & 7;

    for (int i = tid; i < HIDDEN * 64; i += 256) {
        int f = i >> 6, kq = i & 63;
        *(float4*)&sw[f][kq * 4] = w4[f * 64 + kq];
    }
    float4 stg[4];
#pragma unroll
    for (int m = 0; m < 4; ++m) {
        int rr = rs + 32 * m;
        stg[m] = make_float4(0.f, 0.f, 0.f, 0.f);
        if (base + rr < N_NODES) stg[m] = x4[(base + rr) * 64 + ks];
    }
#pragma unroll
    for (int m = 0; m < 4; ++m) *(float4*)&sx[rs + 32 * m][ks * 4] = stg[m];
    __syncthreads();

    const int r0 = tid >> 3;
    const int c0 = tid & 7;
    float acc[4][4] = {};

    for (int p = 0; p < 8; ++p) {
        if (p < 7) {
#pragma unroll
            for (int m = 0; m < 4; ++m) {
                int rr = rs + 32 * m;
                stg[m] = make_float4(0.f, 0.f, 0.f, 0.f);
                if (base + rr < N_NODES) stg[m] = x4[(base + rr) * 64 + (p + 1) * 8 + ks];
            }
        }
#pragma unroll
        for (int kq = 0; kq < 8; ++kq) {
            float4 xa[4], wv[4];
#pragma unroll
            for (int m = 0; m < 4; ++m) xa[m] = *(const float4*)&sx[r0 + 32 * m][kq * 4];
#pragma unroll
            for (int j = 0; j < 4; ++j) wv[j] = *(const float4*)&sw[c0 + 8 * j][(p * 8 + kq) * 4];
#pragma unroll
            for (int m = 0; m < 4; ++m)
#pragma unroll
                for (int j = 0; j < 4; ++j)
                    acc[m][j] += xa[m].x * wv[j].x + xa[m].y * wv[j].y +
                                 xa[m].z * wv[j].z + xa[m].w * wv[j].w;
        }
        __syncthreads();
        if (p < 7) {
#pragma unroll
            for (int m = 0; m < 4; ++m) *(float4*)&sx[rs + 32 * m][ks * 4] = stg[m];
            __syncthreads();
        }
    }

#pragma unroll
    for (int m = 0; m < 4; ++m) {
        size_t r = base + r0 + 32 * m;
        if (r < N_NODES) {
            float ds = dis[r];
#pragma unroll
            for (int j = 0; j < 4; ++j) h[r * HIDDEN + c0 + 8 * j] = acc[m][j] * ds;
        }
    }
}

// ---- FUSED layer-1 gather + gemm2 (h is pre-scaled h' = h*dis) ----
__global__ __launch_bounds__(256) void k_gather1(
        const int2* __restrict__ off2, const int2* __restrict__ csr,
        const float* __restrict__ h, const float* __restrict__ dis,
        const float* __restrict__ b1, const float* __restrict__ W2,
        const int* __restrict__ ocur, const int4* __restrict__ olist,
        float* __restrict__ h2) {
    __shared__ int2 sc[G1CAP];                 // 16384 B csr window
    __shared__ float sw2[EMBED][HIDDEN + 1];   //  2112 B (stride 33)
    __shared__ float sout[G1N][HIDDEN + 1];    //  4224 B relu(out1)
    __shared__ int s_start, s_n, s_ov;
    const int tid = threadIdx.x;
    const int node0 = blockIdx.x * G1N;        // 100000 = 32*3125 exact
    if (tid == 0) {
        int2 a = off2[node0];
        int2 b = off2[node0 + G1N - 1];
        s_start = a.x;
        s_n = b.x + b.y - a.x;
        s_ov = *ocur;
    }
    for (int i = tid; i < EMBED * HIDDEN; i += 256) sw2[i >> 5][i & 31] = W2[i];
    __syncthreads();
    const int start = s_start, n = s_n, ov = min(s_ov, OCAP);
    const bool fit = (n <= G1CAP);
    if (fit) for (int i = tid; i < n; i += 256) sc[i] = csr[start + i];
    __syncthreads();

    const int node = node0 + (tid >> 3);
    const int og = tid & 7;
    float d = dis[node];
    float4 self = *(const float4*)(h + (size_t)node * HIDDEN + og * 4);
    float4 bv = *(const float4*)(b1 + og * 4);
    float4 acc = make_float4(0.f, 0.f, 0.f, 0.f);

    int2 o = off2[node];
    for (int j = 0; j < o.y; ++j) {
        int2 v = fit ? sc[o.x - start + j] : csr[o.x + j];
        float w = __int_as_float(v.y);           // raw ew
        const float4 hv = *(const float4*)(h + (size_t)v.x * HIDDEN + og * 4);
        acc.x += hv.x * w; acc.y += hv.y * w; acc.z += hv.z * w; acc.w += hv.w * w;
    }
    float4 res = make_float4((acc.x + self.x) * d + bv.x,
                             (acc.y + self.y) * d + bv.y,
                             (acc.z + self.z) * d + bv.z,
                             (acc.w + self.w) * d + bv.w);
    if (ov > 0) {  // exact overflow fallback (never taken in practice)
        for (int q = 0; q < ov; ++q) {
            int4 t = olist[q];
            if (t.y == node) {
                float w = __int_as_float(t.z) * d;  // h' includes dis[src]
                const float4 hv = *(const float4*)(h + (size_t)t.x * HIDDEN + og * 4);
                res.x += hv.x * w; res.y += hv.y * w;
                res.z += hv.z * w; res.w += hv.w * w;
            }
        }
    }
    // relu + stage
    *(float4*)&sout[tid >> 3][og * 4] =
        make_float4(fmaxf(res.x, 0.f), fmaxf(res.y, 0.f),
                    fmaxf(res.z, 0.f), fmaxf(res.w, 0.f));
    __syncthreads();
    // h2' = (relu(out1) @ W2^T) * dis : 32 nodes x 16 feats, 2 per thread
    const int n2 = tid >> 3;
    const int f2 = (tid & 7) * 2;
    float a0 = 0.f, a1 = 0.f;
#pragma unroll
    for (int k = 0; k < HIDDEN; ++k) {
        float r = sout[n2][k];
        a0 += r * sw2[f2][k];
        a1 += r * sw2[f2 + 1][k];
    }
    h2[(size_t)(node0 + n2) * EMBED + f2] = a0 * d;
    h2[(size_t)(node0 + n2) * EMBED + f2 + 1] = a1 * d;
}

// ---- layer 2 gather (h2 is pre-scaled h2' = h2*dis): out = gcn2 ----
__global__ __launch_bounds__(256) void k_gather2(
        const int2* __restrict__ off2, const int2* __restrict__ csr,
        const float* __restrict__ h2, const float* __restrict__ dis,
        const float* __restrict__ b2, const int* __restrict__ ocur,
        const int4* __restrict__ olist, float* __restrict__ out) {
    __shared__ int2 sc[G2CAP];
    __shared__ int s_start, s_n, s_ov;
    const int tid = threadIdx.x;
    const int node0 = blockIdx.x * G2N;
    const int lastn = min(node0 + G2N, N_NODES) - 1;
    if (tid == 0) {
        int2 a = off2[node0];
        int2 b = off2[lastn];
        s_start = a.x;
        s_n = b.x + b.y - a.x;
        s_ov = *ocur;
    }
    __syncthreads();
    const int start = s_start, n = s_n, ov = min(s_ov, OCAP);
    const bool fit = (n <= G2CAP);
    if (fit) for (int i = tid; i < n; i += 256) sc[i] = csr[start + i];
    __syncthreads();

    const int node = node0 + (tid >> 2);
    const int og = tid & 3;
    if (node >= N_NODES) return;
    float d = dis[node];
    float4 self = *(const float4*)(h2 + (size_t)node * EMBED + og * 4);
    float4 bv = *(const float4*)(b2 + og * 4);
    float4 acc = make_float4(0.f, 0.f, 0.f, 0.f);

    int2 o = off2[node];
    for (int j = 0; j < o.y; ++j) {
        int2 v = fit ? sc[o.x - start + j] : csr[o.x + j];
        float w = __int_as_float(v.y);           // raw ew
        const float4 hv = *(const float4*)(h2 + (size_t)v.x * EMBED + og * 4);
        acc.x += hv.x * w; acc.y += hv.y * w; acc.z += hv.z * w; acc.w += hv.w * w;
    }
    float4 res = make_float4((acc.x + self.x) * d + bv.x,
                             (acc.y + self.y) * d + bv.y,
                             (acc.z + self.z) * d + bv.z,
                             (acc.w + self.w) * d + bv.w);
    if (ov > 0) {  // exact overflow fallback
        for (int q = 0; q < ov; ++q) {
            int4 t = olist[q];
            if (t.y == node) {
                float w = __int_as_float(t.z) * d;  // h2' includes dis[src]
                const float4 hv = *(const float4*)(h2 + (size_t)t.x * EMBED + og * 4);
                res.x += hv.x * w; res.y += hv.y * w;
                res.z += hv.z * w; res.w += hv.w * w;
            }
        }
    }
    *(float4*)(out + (size_t)node * EMBED + og * 4) = res;
}

extern "C" void kernel_launch(void* const* d_in, const int* in_sizes, int n_in,
                              void* d_out, int out_size, void* d_ws, size_t ws_size,
                              hipStream_t stream) {
    const float* x  = (const float*)d_in[0];
    const int*   ei = (const int*)d_in[1];  // [2, E] int32
    const float* ew = (const float*)d_in[2];
    const float* W1 = (const float*)d_in[3];
    const float* b1 = (const float*)d_in[4];
    const float* W2 = (const float*)d_in[5];
    const float* b2 = (const float*)d_in[6];
    float* out = (float*)d_out;

    const int* row = ei;            // source
    const int* col = ei + N_EDGES;  // target

    // ws layout:
    // off2[N] int2 | binned[NBIN*CAPB] int2 | dis[N] f32 |
    // offm[PBLK*OMS] int | ocur[4] int | olist[OCAP] int4 |
    // big: chunks[PBLK*PEPB] int2  ALIASES  h[32N] + h2[16N]
    int2*  off2   = (int2*)d_ws;
    int2*  binned = off2 + N_NODES;
    float* dis    = (float*)(binned + (size_t)NBIN * CAPB);
    int*   offm   = (int*)(dis + N_NODES);
    int*   ocur   = offm + (size_t)PBLK * OMS;
    int4*  olist  = (int4*)(ocur + 4);
    void*  big    = (void*)(olist + OCAP);
    int2*  chunks = (int2*)big;
    float* h      = (float*)big;               // alias: chunks dead before gemm1
    float* h2     = h + (size_t)N_NODES * HIDDEN;

    const int B = 256;

    k_part<<<PBLK, B, 0, stream>>>(row, col, ew, offm, chunks, ocur);
    k_build<<<NBIN, B, 0, stream>>>(offm, chunks, binned, dis, off2, ocur, olist);
    k_gemm1<<<(N_NODES + GR - 1) / GR, B, 0, stream>>>(x, W1, dis, h);
    k_gather1<<<N_NODES / G1N, B, 0, stream>>>(off2, binned, h, dis, b1, W2, ocur, olist, h2);
    k_gather2<<<(N_NODES + G2N - 1) / G2N, B, 0, stream>>>(off2, binned, h2, dis, b2, ocur, olist, out);
}